// Round 8
// baseline (531.326 us; speedup 1.0000x reference)
//
#include <hip/hip_runtime.h>

typedef unsigned short u16;
typedef unsigned int   u32;

#define SEQ 2048
#define EMB 2048
#define TD  6144

using bf16x8 = __attribute__((ext_vector_type(8))) __bf16;
using f32x16 = __attribute__((ext_vector_type(16))) float;
using u16x8v = __attribute__((ext_vector_type(8))) u16;

typedef __attribute__((address_space(1))) const void* gas_t;
typedef __attribute__((address_space(3))) void*       las_t;
#define GLOAD16(g, l) __builtin_amdgcn_global_load_lds((gas_t)(g), (las_t)(l), 16, 0, 0)

__device__ __forceinline__ u16 f2bf(float f) {
  u32 u = __float_as_uint(f);
  u += 0x7fffu + ((u >> 16) & 1u);   // round-to-nearest-even
  return (u16)(u >> 16);
}

// ---------------- cast x (fp32) -> xb (bf16) ----------------
__global__ __launch_bounds__(256) void cast_x_kern(const float* __restrict__ x,
                                                   u16* __restrict__ xb) {
  size_t i = ((size_t)blockIdx.x * 256 + threadIdx.x) * 4;
  float4 v = *(const float4*)(x + i);
  ushort4 u;
  u.x = f2bf(v.x); u.y = f2bf(v.y); u.z = f2bf(v.z); u.w = f2bf(v.w);
  *(ushort4*)(xb + i) = u;
}

// ---------------- cast + transpose W [EMB][TD] -> Wt [TD][EMB] bf16 ----------------
__global__ __launch_bounds__(256) void castT_W_kern(const float* __restrict__ W,
                                                    u16* __restrict__ Wt) {
  __shared__ float t[64][65];
  int c0 = blockIdx.x * 64, r0 = blockIdx.y * 64;
  int tid = threadIdx.x;
#pragma unroll
  for (int i = 0; i < 4; ++i) {
    int flat = i * 1024 + tid * 4;
    int r = flat >> 6, c = flat & 63;
    float4 v = *(const float4*)(W + (size_t)(r0 + r) * TD + c0 + c);
    t[r][c] = v.x; t[r][c + 1] = v.y; t[r][c + 2] = v.z; t[r][c + 3] = v.w;
  }
  __syncthreads();
#pragma unroll
  for (int i = 0; i < 4; ++i) {
    int flat = i * 1024 + tid * 4;
    int wr = flat >> 6, wc = flat & 63;
    ushort4 u;
    u.x = f2bf(t[wc + 0][wr]); u.y = f2bf(t[wc + 1][wr]);
    u.z = f2bf(t[wc + 2][wr]); u.w = f2bf(t[wc + 3][wr]);
    *(ushort4*)(Wt + (size_t)(c0 + wr) * EMB + r0 + wc) = u;
  }
}

// ------------- 256x256 NT GEMM, 32x32x16 MFMA, derived waits, minimal barriers -------------
// C[i][j] = sum_k A[i][k] * Bt[j][k]
// R8: (a) mfma_f32_32x32x16_bf16 (half the MFMA instrs, ~15% faster pipe; frag bytes same)
//     (b) MODE 0 persistent: grid 256, 3 output tiles/block (cols c, c+8, c+16; same rows).
//         Global kt 0..95; stage schedule translation-invariant, B-pointer wraps per 32.
//         Mid-epilogues (qk tiles, direct stores) overlap staging; v tile last -> LDS free.
// Frag layout (verified m74/m101): C col=lane&31, row=(reg&3)+8*(reg>>2)+4*(lane>>5);
// A/B row=lane&31, k=(lane>>5)*8+j.
// MODE 0: [qk | vT] = xb @ Wt^T + bias. grid 256.
// MODE 1: att = scale * q @ k^T (strides 4096), causal 256-tile triangle. grid 144
// MODE 2: y = P @ vT^T, K = (qi+1)*256. grid 256
template <int MODE>
__global__ __launch_bounds__(512, 2) void gemm256(const u16* __restrict__ Ab,
                                                  const u16* __restrict__ Bb,
                                                  void* __restrict__ Cb,
                                                  void* __restrict__ Cb2,
                                                  const float* __restrict__ bias) {
  // per buffer: A tile 256x64 bf16 (32KB) then B tile 256x64 (32KB); x2 buffers = 128KB
  __shared__ char lds[2][65536];

  constexpr int lda = (MODE == 0) ? EMB : 4096;
  constexpr int ldb = (MODE == 0) ? EMB : (MODE == 1) ? 4096 : SEQ;
  constexpr int NWG = (MODE == 0) ? 256 : (MODE == 1) ? 144 : 256;
  constexpr int CPX = NWG / 8;

  int bid = blockIdx.x;
  int wg = (bid & 7) * CPX + (bid >> 3);          // XCD-aware swizzle (NWG%8==0)

  const u16 *A, *Bt;
  int row0, col0 = 0, c0 = 0, total;
  size_t coff = 0;
  if constexpr (MODE == 0) {
    A = Ab; Bt = Bb;
    row0 = (wg >> 3) * 256; c0 = wg & 7; total = 96;   // 3 tiles x 32 K-steps
  } else if constexpr (MODE == 1) {
    int b = wg / 36, tq = wg % 36;
    int qi = (int)((sqrtf(8.f * (float)tq + 1.f) - 1.f) * 0.5f);
    while ((qi + 1) * (qi + 2) / 2 <= tq) ++qi;
    while (qi * (qi + 1) / 2 > tq) --qi;
    int kj = tq - qi * (qi + 1) / 2;
    A = Ab + (size_t)b * SEQ * 4096;     // q slice (cols 0..2047 of qk)
    Bt = A + 2048;                       // k slice (cols 2048..4095)
    row0 = qi * 256; col0 = kj * 256; total = 32;
    coff = (size_t)b * SEQ * SEQ;
  } else {
    int b = wg >> 6, qi = (wg >> 3) & 7, nj = wg & 7;
    A = Ab + (size_t)b * SEQ * 4096;     // P, row stride 4096 u16
    Bt = Bb + (size_t)b * SEQ * SEQ;     // vT
    row0 = qi * 256; col0 = nj * 256; total = (qi + 1) * 4;
    coff = (size_t)b * SEQ * SEQ;
  }

  int tid = threadIdx.x;
  int wave = tid >> 6, lane = tid & 63;
  int wm = wave >> 2, wn = wave & 3;               // 2 x 4 wave grid, 128x64 out each
  int l31 = lane & 31, hi = lane >> 5;

  // Stage-bundle LDS byte bases (uniform per wave). One bundle = 8KB block-wide.
  // b0..b3: B tile.  b4..b7: A quadrants {rows q*32..q*32+31} u {128+q*32..+31}.
  int sbase[8];
#pragma unroll
  for (int i = 0; i < 4; ++i) sbase[i] = 32768 + i * 8192 + wave * 1024;
#pragma unroll
  for (int i = 0; i < 4; ++i)
    sbase[4 + i] = i * 4096 + ((wave < 4) ? wave * 1024 : 16384 + (wave - 4) * 1024);

  // linear LDS dest + inverse-swizzled global source (rule #21); swizzle: byte ^= (row&7)<<4
  auto stageb = [&](int bi, int ktt, int buf) {
    int ob = sbase[bi];
    int obl = ob + lane * 16;
    int row = (obl & 32767) >> 7;
    int cb = obl & 127;
    int tin = (MODE == 0) ? (ktt & 31) : ktt;
    int c = ((cb ^ ((row & 7) << 4)) >> 1) + tin * 64;
    const u16* src;
    if (ob < 32768) {
      src = A + (size_t)(row0 + row) * lda + c;
    } else {
      int cB = (MODE == 0) ? (c0 + 8 * (ktt >> 5)) * 256 : col0;
      src = Bt + (size_t)(cB + row) * ldb + c;
    }
    GLOAD16(src, (char*)&lds[buf][0] + ob);
  };

  auto ldA = [&](int buf, int rr, int ks) -> bf16x8 {
    int cb = ks * 32 + hi * 16;
    return *(const bf16x8*)&lds[buf][rr * 128 + (cb ^ ((rr & 7) << 4))];
  };
  auto ldB = [&](int buf, int rr, int ks) -> bf16x8 {
    int cb = ks * 32 + hi * 16;
    return *(const bf16x8*)&lds[buf][32768 + rr * 128 + (cb ^ ((rr & 7) << 4))];
  };

  f32x16 acc[4][2];
#pragma unroll
  for (int m = 0; m < 4; ++m)
#pragma unroll
    for (int n = 0; n < 2; ++n) acc[m][n] = (f32x16)(0.f);

  int rb = row0 + wm * 128, cb0w = wn * 64;   // cb0w: within-tile col base

  // qk mid-epilogue (MODE 0, tiles 0/1): direct stores from acc, then re-zero
  auto dump_qk = [&](int colbase) {
    u16* C = (u16*)Cb;
#pragma unroll
    for (int n = 0; n < 2; ++n) {
      int col = colbase + cb0w + n * 32 + l31;
      float bv = bias[col];
#pragma unroll
      for (int m = 0; m < 4; ++m)
#pragma unroll
        for (int r = 0; r < 16; ++r) {
          int row = rb + m * 32 + (r & 3) + 8 * (r >> 2) + 4 * hi;
          C[(size_t)row * 4096 + col] = f2bf(acc[m][n][r] + bv);
        }
    }
#pragma unroll
    for (int m = 0; m < 4; ++m)
#pragma unroll
      for (int n = 0; n < 2; ++n) acc[m][n] = (f32x16)(0.f);
  };

  // prologue: kt0 fully, kt1 b0..b5; vmcnt(6) -> kt0 landed
#pragma unroll
  for (int bi = 0; bi < 8; ++bi) stageb(bi, 0, 0);
#pragma unroll
  for (int bi = 0; bi < 6; ++bi) stageb(bi, 1, 1);
  asm volatile("s_waitcnt vmcnt(6)" ::: "memory");
  __builtin_amdgcn_s_barrier();

  bf16x8 bfg[2][4];
  for (int kt = 0; kt < total; ++kt) {
    int cur = kt & 1, nxt = cur ^ 1;
    bool pf1 = (kt + 1 < total), pf2 = (kt + 2 < total);
    bf16x8 afg[4];

    // ---- p0: read B(8) + A-quad0(4); stage (kt+1).b6,b7 -> nxt; MFMA q0; BARRIER ----
#pragma unroll
    for (int n = 0; n < 2; ++n)
#pragma unroll
      for (int ks = 0; ks < 4; ++ks)
        bfg[n][ks] = ldB(cur, wn * 64 + n * 32 + l31, ks);
#pragma unroll
    for (int ks = 0; ks < 4; ++ks)
      afg[ks] = ldA(cur, wm * 128 + l31, ks);
    if (pf1) { stageb(6, kt + 1, nxt); stageb(7, kt + 1, nxt); }
    __builtin_amdgcn_s_setprio(1);
#pragma unroll
    for (int n = 0; n < 2; ++n)
#pragma unroll
      for (int ks = 0; ks < 4; ++ks)
        acc[0][n] = __builtin_amdgcn_mfma_f32_32x32x16_bf16(
            afg[ks], bfg[n][ks], acc[0][n], 0, 0, 0);
    __builtin_amdgcn_s_setprio(0);
    __builtin_amdgcn_s_barrier();

    // ---- p1: read A-quad1; stage (kt+2).b0,b1 -> cur; MFMA q1 (no barrier) ----
#pragma unroll
    for (int ks = 0; ks < 4; ++ks)
      afg[ks] = ldA(cur, wm * 128 + 32 + l31, ks);
    if (pf2) { stageb(0, kt + 2, cur); stageb(1, kt + 2, cur); }
    __builtin_amdgcn_s_setprio(1);
#pragma unroll
    for (int n = 0; n < 2; ++n)
#pragma unroll
      for (int ks = 0; ks < 4; ++ks)
        acc[1][n] = __builtin_amdgcn_mfma_f32_32x32x16_bf16(
            afg[ks], bfg[n][ks], acc[1][n], 0, 0, 0);
    __builtin_amdgcn_s_setprio(0);

    // ---- p2: read A-quad2; stage (kt+2).b2,b3 -> cur; MFMA q2; BARRIER ----
#pragma unroll
    for (int ks = 0; ks < 4; ++ks)
      afg[ks] = ldA(cur, wm * 128 + 64 + l31, ks);
    if (pf2) { stageb(2, kt + 2, cur); stageb(3, kt + 2, cur); }
    __builtin_amdgcn_s_setprio(1);
#pragma unroll
    for (int n = 0; n < 2; ++n)
#pragma unroll
      for (int ks = 0; ks < 4; ++ks)
        acc[2][n] = __builtin_amdgcn_mfma_f32_32x32x16_bf16(
            afg[ks], bfg[n][ks], acc[2][n], 0, 0, 0);
    __builtin_amdgcn_s_setprio(0);
    __builtin_amdgcn_s_barrier();

    // ---- p3: read A-quad3; stage (kt+2).b4,b5 -> cur; MFMA q3; vmcnt; BARRIER ----
#pragma unroll
    for (int ks = 0; ks < 4; ++ks)
      afg[ks] = ldA(cur, wm * 128 + 96 + l31, ks);
    if (pf2) { stageb(4, kt + 2, cur); stageb(5, kt + 2, cur); }
    __builtin_amdgcn_s_setprio(1);
#pragma unroll
    for (int n = 0; n < 2; ++n)
#pragma unroll
      for (int ks = 0; ks < 4; ++ks)
        acc[3][n] = __builtin_amdgcn_mfma_f32_32x32x16_bf16(
            afg[ks], bfg[n][ks], acc[3][n], 0, 0, 0);
    __builtin_amdgcn_s_setprio(0);
    if (pf2)      asm volatile("s_waitcnt vmcnt(6)" ::: "memory");
    else if (pf1) asm volatile("s_waitcnt vmcnt(0)" ::: "memory");
    __builtin_amdgcn_s_barrier();

    if constexpr (MODE == 0) {
      if ((kt & 31) == 31 && kt != total - 1)
        dump_qk((c0 + 8 * (kt >> 5)) * 256);     // qk tiles 0,1; overlaps staging
    }
  }

  if constexpr (MODE == 0) {
    // final tile is ALWAYS v (col c0+16 >= 16): vT[b][d][n] via in-LDS transpose.
    int col0v = (c0 + 16) * 256;
    u16* vTb = (u16*)Cb2 + (size_t)(row0 >> 11) * SEQ * SEQ;
    int nbase = row0 & 2047;
    u16 (*T)[264] = (u16(*)[264])(&lds[0][0]);   // 128 x 264 u16 = 66KB (pipeline drained)
    int half = wn >> 1;
    int dloc0 = (wn & 1) * 64;
#pragma unroll
    for (int hh = 0; hh < 2; ++hh) {
      if (half == hh) {
#pragma unroll
        for (int n = 0; n < 2; ++n) {
          int col = col0v + cb0w + n * 32 + l31;
          float bv = bias[col];
          int dl = dloc0 + n * 32 + l31;
#pragma unroll
          for (int m = 0; m < 4; ++m)
#pragma unroll
            for (int r = 0; r < 16; ++r)
              T[dl][wm * 128 + m * 32 + (r & 3) + 8 * (r >> 2) + 4 * hi] =
                  f2bf(acc[m][n][r] + bv);
        }
      }
      __syncthreads();
      int dl = tid >> 5, nn = (tid & 31) * 8;
#pragma unroll
      for (int it = 0; it < 8; ++it) {
        int loc = it * 16 + dl;
        *(u16x8v*)&vTb[(size_t)(col0v - 4096 + hh * 128 + loc) * SEQ + nbase + nn] =
            *(const u16x8v*)&T[loc][nn];
      }
      __syncthreads();
    }
  } else if constexpr (MODE == 1) {
    float* C = (float*)Cb + coff;
    const float scale = 0.022097086912079608f;   // 1/sqrt(2048)
#pragma unroll
    for (int n = 0; n < 2; ++n) {
      int col = col0 + cb0w + n * 32 + l31;
#pragma unroll
      for (int m = 0; m < 4; ++m)
#pragma unroll
        for (int r = 0; r < 16; ++r) {
          int row = rb + m * 32 + (r & 3) + 8 * (r >> 2) + 4 * hi;
          C[(size_t)row * SEQ + col] = acc[m][n][r] * scale;
        }
    }
  } else {
    float* C = (float*)Cb + coff;
#pragma unroll
    for (int n = 0; n < 2; ++n) {
      int col = col0 + cb0w + n * 32 + l31;
#pragma unroll
      for (int m = 0; m < 4; ++m)
#pragma unroll
        for (int r = 0; r < 16; ++r) {
          int row = rb + m * 32 + (r & 3) + 8 * (r >> 2) + 4 * hi;
          C[(size_t)row * SEQ + col] = acc[m][n][r];
        }
    }
  }
}

// ---------------- row softmax: att fp32 -> P bf16 (in place, stride 4096), denom ----------------
// extent is 256-granular to match the 256-tile GEMMs; masked entries produce exp->0.
__global__ __launch_bounds__(256) void softmax_kern(const float* __restrict__ att,
                                                    u16* __restrict__ P,
                                                    float* __restrict__ denom) {
  int row = blockIdx.x;          // b*SEQ + q
  int q = row & (SEQ - 1);
  const float* arow = att + (size_t)row * SEQ;
  u16* prow = P + (size_t)row * 4096;
  int jlen = ((q >> 8) + 1) << 8;          // 256-tile-aligned row extent
  int tid = threadIdx.x;
  int j0 = tid * 4, j1 = tid * 4 + 1024;
  float NI = -__builtin_inff();
  float4 a0 = make_float4(NI, NI, NI, NI), a1 = a0;
  if (j0 < jlen) a0 = *(const float4*)(arow + j0);
  if (j1 < jlen) a1 = *(const float4*)(arow + j1);
  if (j0 + 0 > q) a0.x = NI;
  if (j0 + 1 > q) a0.y = NI;
  if (j0 + 2 > q) a0.z = NI;
  if (j0 + 3 > q) a0.w = NI;
  if (j1 + 0 > q) a1.x = NI;
  if (j1 + 1 > q) a1.y = NI;
  if (j1 + 2 > q) a1.z = NI;
  if (j1 + 3 > q) a1.w = NI;
  float mx = fmaxf(fmaxf(fmaxf(a0.x, a0.y), fmaxf(a0.z, a0.w)),
                   fmaxf(fmaxf(a1.x, a1.y), fmaxf(a1.z, a1.w)));
#pragma unroll
  for (int off = 32; off; off >>= 1) mx = fmaxf(mx, __shfl_xor(mx, off, 64));
  __shared__ float red[8];
  int wv = tid >> 6;
  if ((tid & 63) == 0) red[wv] = mx;
  __syncthreads();
  mx = fmaxf(fmaxf(red[0], red[1]), fmaxf(red[2], red[3]));
  a0.x = expf(a0.x - mx); a0.y = expf(a0.y - mx);
  a0.z = expf(a0.z - mx); a0.w = expf(a0.w - mx);
  a1.x = expf(a1.x - mx); a1.y = expf(a1.y - mx);
  a1.z = expf(a1.z - mx); a1.w = expf(a1.w - mx);
  float s = (a0.x + a0.y + a0.z + a0.w) + (a1.x + a1.y + a1.z + a1.w);
#pragma unroll
  for (int off = 32; off; off >>= 1) s += __shfl_xor(s, off, 64);
  if ((tid & 63) == 0) red[4 + wv] = s;
  __syncthreads();                          // fences all arow reads before P writes
  s = red[4] + red[5] + red[6] + red[7];
  float inv = 1.0f / s;
  if (j0 < jlen) {
    ushort4 u;
    u.x = f2bf(a0.x * inv); u.y = f2bf(a0.y * inv);
    u.z = f2bf(a0.z * inv); u.w = f2bf(a0.w * inv);
    *(ushort4*)(prow + j0) = u;
  }
  if (j1 < jlen) {
    ushort4 u;
    u.x = f2bf(a1.x * inv); u.y = f2bf(a1.y * inv);
    u.z = f2bf(a1.z * inv); u.w = f2bf(a1.w * inv);
    *(ushort4*)(prow + j1) = u;
  }
  if (tid == 0) denom[row] = s;
}

extern "C" void kernel_launch(void* const* d_in, const int* in_sizes, int n_in,
                              void* d_out, int out_size, void* d_ws, size_t ws_size,
                              hipStream_t stream) {
  const float* x    = (const float*)d_in[0];
  const float* W    = (const float*)d_in[1];
  const float* bias = (const float*)d_in[2];

  // ws layout (201,326,592 B):
  //  [0,         67108864)  qk bf16 [8192][4096] (q cols 0..2047, k cols 2048..4095)
  //  [67108864, 100663296)  vT bf16 [4][2048][2048]   (written by gemm<0> epilogue)
  //  [100663296,134217728)  xb bf16 [8192][2048]      (dead after gemm<0>)
  //  [134217728,201326592)  phase1: Wt bf16 (first 25MB, dead after gemm<0>)
  //                         phase2: att fp32 / P bf16 in-place (row stride 4096 u16)
  if (ws_size < 201326592u) return;

  char* w = (char*)d_ws;
  u16*   qk  = (u16*)w;
  u16*   vT  = (u16*)(w + 67108864);
  u16*   xb  = (u16*)(w + 100663296);
  u16*   Wt  = (u16*)(w + 134217728);
  float* att = (float*)(w + 134217728);
  u16*   P   = (u16*)(w + 134217728);

  float* y     = (float*)d_out;
  float* denom = y + (size_t)4 * SEQ * SEQ;

  cast_x_kern<<<16384, 256, 0, stream>>>(x, xb);
  castT_W_kern<<<dim3(96, 32), 256, 0, stream>>>(W, Wt);
  gemm256<0><<<256, 512, 0, stream>>>(xb, Wt, qk, vT, bias);
  gemm256<1><<<144, 512, 0, stream>>>(qk, nullptr, att, nullptr, nullptr);
  softmax_kern<<<8192, 256, 0, stream>>>(att, P, denom);
  gemm256<2><<<256, 512, 0, stream>>>(P, vT, y, nullptr, nullptr);
}

// Round 9
// 353.323 us; speedup vs baseline: 1.5038x; 1.5038x over previous
//
#include <hip/hip_runtime.h>

typedef unsigned short u16;
typedef unsigned int   u32;

#define SEQ 2048
#define EMB 2048
#define TD  6144

using bf16x8 = __attribute__((ext_vector_type(8))) __bf16;
using f32x4  = __attribute__((ext_vector_type(4))) float;
using u16x8v = __attribute__((ext_vector_type(8))) u16;

typedef __attribute__((address_space(1))) const void* gas_t;
typedef __attribute__((address_space(3))) void*       las_t;
#define GLOAD16(g, l) __builtin_amdgcn_global_load_lds((gas_t)(g), (las_t)(l), 16, 0, 0)

__device__ __forceinline__ u16 f2bf(float f) {
  u32 u = __float_as_uint(f);
  u += 0x7fffu + ((u >> 16) & 1u);   // round-to-nearest-even
  return (u16)(u >> 16);
}

// ---------------- cast x (fp32) -> xb (bf16) ----------------
__global__ __launch_bounds__(256) void cast_x_kern(const float* __restrict__ x,
                                                   u16* __restrict__ xb) {
  size_t i = ((size_t)blockIdx.x * 256 + threadIdx.x) * 4;
  float4 v = *(const float4*)(x + i);
  ushort4 u;
  u.x = f2bf(v.x); u.y = f2bf(v.y); u.z = f2bf(v.z); u.w = f2bf(v.w);
  *(ushort4*)(xb + i) = u;
}

// ---------------- cast + transpose W [EMB][TD] -> Wt [TD][EMB] bf16 ----------------
__global__ __launch_bounds__(256) void castT_W_kern(const float* __restrict__ W,
                                                    u16* __restrict__ Wt) {
  __shared__ float t[64][65];
  int c0 = blockIdx.x * 64, r0 = blockIdx.y * 64;
  int tid = threadIdx.x;
#pragma unroll
  for (int i = 0; i < 4; ++i) {
    int flat = i * 1024 + tid * 4;
    int r = flat >> 6, c = flat & 63;
    float4 v = *(const float4*)(W + (size_t)(r0 + r) * TD + c0 + c);
    t[r][c] = v.x; t[r][c + 1] = v.y; t[r][c + 2] = v.z; t[r][c + 3] = v.w;
  }
  __syncthreads();
#pragma unroll
  for (int i = 0; i < 4; ++i) {
    int flat = i * 1024 + tid * 4;
    int wr = flat >> 6, wc = flat & 63;
    ushort4 u;
    u.x = f2bf(t[wc + 0][wr]); u.y = f2bf(t[wc + 1][wr]);
    u.z = f2bf(t[wc + 2][wr]); u.w = f2bf(t[wc + 3][wr]);
    *(ushort4*)(Wt + (size_t)(c0 + wr) * EMB + r0 + wc) = u;
  }
}

// ---------------- 256x256 8-phase NT GEMM, derived waits + minimal barriers ----------------
// C[i][j] = sum_k A[i][k] * Bt[j][k]
// R9 change vs R7: MODE 0 block mapping is column-major within each XCD (xcd owns 3 cols x
// 32 rows). Co-resident blocks on an XCD share ONE 1MB B-panel (L2-resident); A streams
// from L3. Kills the ~300MB avoidable HBM B-re-fetch seen in R7 (FETCH_SIZE 378MB).
// Schedule identical to R7: barriers 3 per K-tile (p0-end, p2-end, p3-end), compiler lgkm
// waits, vmcnt(6) derived wait at p3.
// MODE 0: [qk | vT] = xb @ Wt^T + bias. col<4096 -> qk[8192][4096] bf16;
//         col>=4096 -> vT[b][d][n] bf16 via in-LDS transpose.
// MODE 1: att = scale * q @ k^T over qk (strides 4096), causal 256-tile triangle. grid 144
// MODE 2: y = P @ vT^T, K = (qi+1)*256. grid 256
template <int MODE>
__global__ __launch_bounds__(512, 2) void gemm256(const u16* __restrict__ Ab,
                                                  const u16* __restrict__ Bb,
                                                  void* __restrict__ Cb,
                                                  void* __restrict__ Cb2,
                                                  const float* __restrict__ bias) {
  // per buffer: A tile 256x64 bf16 (32KB) then B tile 256x64 (32KB); x2 buffers = 128KB
  __shared__ char lds[2][65536];

  constexpr int lda = (MODE == 0) ? EMB : 4096;
  constexpr int ldb = (MODE == 0) ? EMB : (MODE == 1) ? 4096 : SEQ;
  constexpr int NWG = (MODE == 0) ? 768 : (MODE == 1) ? 144 : 256;
  constexpr int CPX = NWG / 8;

  int bid = blockIdx.x;
  int wg = (bid & 7) * CPX + (bid >> 3);          // XCD-aware swizzle (NWG%8==0)

  const u16 *A, *Bt;
  int row0, col0, nk;
  size_t coff = 0;
  if constexpr (MODE == 0) {
    A = Ab; Bt = Bb;
    // column-major per XCD: xcd owns cols [xcd*3, xcd*3+3), rows walked fastest.
    int xcd = bid & 7, idx = bid >> 3;            // idx 0..95
    row0 = (idx & 31) * 256;
    col0 = (xcd * 3 + (idx >> 5)) * 256;
    nk = EMB / 64;
  } else if constexpr (MODE == 1) {
    int b = wg / 36, tq = wg % 36;
    int qi = (int)((sqrtf(8.f * (float)tq + 1.f) - 1.f) * 0.5f);
    while ((qi + 1) * (qi + 2) / 2 <= tq) ++qi;
    while (qi * (qi + 1) / 2 > tq) --qi;
    int kj = tq - qi * (qi + 1) / 2;
    A = Ab + (size_t)b * SEQ * 4096;     // q slice (cols 0..2047 of qk)
    Bt = A + 2048;                       // k slice (cols 2048..4095)
    row0 = qi * 256; col0 = kj * 256; nk = EMB / 64;
    coff = (size_t)b * SEQ * SEQ;
  } else {
    int b = wg >> 6, qi = (wg >> 3) & 7, nj = wg & 7;
    A = Ab + (size_t)b * SEQ * 4096;     // P, row stride 4096 u16
    Bt = Bb + (size_t)b * SEQ * SEQ;     // vT
    row0 = qi * 256; col0 = nj * 256; nk = (qi + 1) * 4;
    coff = (size_t)b * SEQ * SEQ;
  }

  int tid = threadIdx.x;
  int wave = tid >> 6, lane = tid & 63;
  int wm = wave >> 2, wn = wave & 3;               // 2 x 4 wave grid, 128x64 out each

  // Stage-bundle LDS byte bases (uniform per wave). One bundle = 8KB block-wide.
  // b0..b3: B tile.  b4..b7: A quadrants {rows q*32..q*32+31} u {128+q*32..+31}.
  int sbase[8];
#pragma unroll
  for (int i = 0; i < 4; ++i) sbase[i] = 32768 + i * 8192 + wave * 1024;
#pragma unroll
  for (int i = 0; i < 4; ++i)
    sbase[4 + i] = i * 4096 + ((wave < 4) ? wave * 1024 : 16384 + (wave - 4) * 1024);

  // linear LDS dest + inverse-swizzled global source (rule #21); swizzle: byte ^= (row&7)<<4
  auto stageb = [&](int bi, int t, int buf) {
    int ob = sbase[bi];
    int obl = ob + lane * 16;
    int row = (obl & 32767) >> 7;
    int cb = obl & 127;
    int c = ((cb ^ ((row & 7) << 4)) >> 1) + t * 64;
    const u16* src = (ob < 32768) ? (A + (size_t)(row0 + row) * lda + c)
                                  : (Bt + (size_t)(col0 + row) * ldb + c);
    GLOAD16(src, (char*)&lds[buf][0] + ob);
  };

  auto ldA = [&](int buf, int rr, int ks) -> bf16x8 {
    int cb = ks * 64 + (lane >> 4) * 16;
    return *(const bf16x8*)&lds[buf][rr * 128 + (cb ^ ((rr & 7) << 4))];
  };
  auto ldB = [&](int buf, int rr, int ks) -> bf16x8 {
    int cb = ks * 64 + (lane >> 4) * 16;
    return *(const bf16x8*)&lds[buf][32768 + rr * 128 + (cb ^ ((rr & 7) << 4))];
  };

  f32x4 acc[8][4];
#pragma unroll
  for (int m = 0; m < 8; ++m)
#pragma unroll
    for (int n = 0; n < 4; ++n) acc[m][n] = (f32x4){0.f, 0.f, 0.f, 0.f};

  // prologue: tile0 fully, tile1 b0..b5; vmcnt(6) -> tile0 landed
#pragma unroll
  for (int bi = 0; bi < 8; ++bi) stageb(bi, 0, 0);
#pragma unroll
  for (int bi = 0; bi < 6; ++bi) stageb(bi, 1, 1);
  asm volatile("s_waitcnt vmcnt(6)" ::: "memory");
  __builtin_amdgcn_s_barrier();

  bf16x8 bfg[4][2];
  for (int t = 0; t < nk; ++t) {
    int cur = t & 1, nxt = cur ^ 1;
    bool pf1 = (t + 1 < nk), pf2 = (t + 2 < nk);
    bf16x8 afg[2][2];

    // ---- p0: read B(8) + A-quad0(4); stage t+1.b6,b7 -> nxt; MFMA q0; BARRIER ----
#pragma unroll
    for (int n = 0; n < 4; ++n)
#pragma unroll
      for (int ks = 0; ks < 2; ++ks)
        bfg[n][ks] = ldB(cur, wn * 64 + n * 16 + (lane & 15), ks);
#pragma unroll
    for (int m = 0; m < 2; ++m)
#pragma unroll
      for (int ks = 0; ks < 2; ++ks)
        afg[m][ks] = ldA(cur, wm * 128 + m * 16 + (lane & 15), ks);
    if (pf1) { stageb(6, t + 1, nxt); stageb(7, t + 1, nxt); }
    __builtin_amdgcn_s_setprio(1);
#pragma unroll
    for (int m = 0; m < 2; ++m)
#pragma unroll
      for (int n = 0; n < 4; ++n)
#pragma unroll
        for (int ks = 0; ks < 2; ++ks)
          acc[m][n] = __builtin_amdgcn_mfma_f32_16x16x32_bf16(
              afg[m][ks], bfg[n][ks], acc[m][n], 0, 0, 0);
    __builtin_amdgcn_s_setprio(0);
    __builtin_amdgcn_s_barrier();

    // ---- p1: read A-quad1; stage t+2.b0,b1 -> cur; MFMA q1 (no barrier) ----
#pragma unroll
    for (int m = 0; m < 2; ++m)
#pragma unroll
      for (int ks = 0; ks < 2; ++ks)
        afg[m][ks] = ldA(cur, wm * 128 + (2 + m) * 16 + (lane & 15), ks);
    if (pf2) { stageb(0, t + 2, cur); stageb(1, t + 2, cur); }
    __builtin_amdgcn_s_setprio(1);
#pragma unroll
    for (int m = 0; m < 2; ++m)
#pragma unroll
      for (int n = 0; n < 4; ++n)
#pragma unroll
        for (int ks = 0; ks < 2; ++ks)
          acc[2 + m][n] = __builtin_amdgcn_mfma_f32_16x16x32_bf16(
              afg[m][ks], bfg[n][ks], acc[2 + m][n], 0, 0, 0);
    __builtin_amdgcn_s_setprio(0);

    // ---- p2: read A-quad2; stage t+2.b2,b3 -> cur; MFMA q2; BARRIER ----
#pragma unroll
    for (int m = 0; m < 2; ++m)
#pragma unroll
      for (int ks = 0; ks < 2; ++ks)
        afg[m][ks] = ldA(cur, wm * 128 + (4 + m) * 16 + (lane & 15), ks);
    if (pf2) { stageb(2, t + 2, cur); stageb(3, t + 2, cur); }
    __builtin_amdgcn_s_setprio(1);
#pragma unroll
    for (int m = 0; m < 2; ++m)
#pragma unroll
      for (int n = 0; n < 4; ++n)
#pragma unroll
        for (int ks = 0; ks < 2; ++ks)
          acc[4 + m][n] = __builtin_amdgcn_mfma_f32_16x16x32_bf16(
              afg[m][ks], bfg[n][ks], acc[4 + m][n], 0, 0, 0);
    __builtin_amdgcn_s_setprio(0);
    __builtin_amdgcn_s_barrier();

    // ---- p3: read A-quad3; stage t+2.b4,b5 -> cur; MFMA q3; vmcnt; BARRIER ----
#pragma unroll
    for (int m = 0; m < 2; ++m)
#pragma unroll
      for (int ks = 0; ks < 2; ++ks)
        afg[m][ks] = ldA(cur, wm * 128 + (6 + m) * 16 + (lane & 15), ks);
    if (pf2) { stageb(4, t + 2, cur); stageb(5, t + 2, cur); }
    __builtin_amdgcn_s_setprio(1);
#pragma unroll
    for (int m = 0; m < 2; ++m)
#pragma unroll
      for (int n = 0; n < 4; ++n)
#pragma unroll
        for (int ks = 0; ks < 2; ++ks)
          acc[6 + m][n] = __builtin_amdgcn_mfma_f32_16x16x32_bf16(
              afg[m][ks], bfg[n][ks], acc[6 + m][n], 0, 0, 0);
    __builtin_amdgcn_s_setprio(0);
    if (pf2)      asm volatile("s_waitcnt vmcnt(6)" ::: "memory");
    else if (pf1) asm volatile("s_waitcnt vmcnt(0)" ::: "memory");
    __builtin_amdgcn_s_barrier();
  }

  int ln = lane & 15;
  int l4 = (lane >> 4) << 2;
  int rb = row0 + wm * 128, cb0 = col0 + wn * 64;
  if constexpr (MODE == 0) {
    if (col0 < 4096) {
      // q/k tile -> qk buffer [8192][4096]
      u16* C = (u16*)Cb;
#pragma unroll
      for (int n = 0; n < 4; ++n) {
        float bv = bias[cb0 + n * 16 + ln];
#pragma unroll
        for (int m = 0; m < 8; ++m)
#pragma unroll
          for (int r = 0; r < 4; ++r)
            C[(size_t)(rb + m * 16 + l4 + r) * 4096 + cb0 + n * 16 + ln] =
                f2bf(acc[m][n][r] + bv);
      }
    } else {
      // v tile -> vT[b][d][n] via in-LDS transpose (two 128-d passes)
      u16* vTb = (u16*)Cb2 + (size_t)(row0 >> 11) * SEQ * SEQ;
      int nbase = row0 & 2047;
      u16 (*T)[264] = (u16(*)[264])(&lds[0][0]);     // 128 x 264 u16 = 66KB of 128KB
      int half = wn >> 1;                             // which d-half this wave holds
      int dloc0 = (wn & 1) * 64;
#pragma unroll
      for (int hh = 0; hh < 2; ++hh) {
        if (half == hh) {
#pragma unroll
          for (int n = 0; n < 4; ++n) {
            float bv = bias[cb0 + n * 16 + ln];
            int dl = dloc0 + n * 16 + ln;
#pragma unroll
            for (int m = 0; m < 8; ++m) {
              int nn = wm * 128 + m * 16 + l4;
#pragma unroll
              for (int r = 0; r < 4; ++r)
                T[dl][nn + r] = f2bf(acc[m][n][r] + bv);
            }
          }
        }
        __syncthreads();
        int dl = tid >> 5, nn = (tid & 31) * 8;
#pragma unroll
        for (int it = 0; it < 8; ++it) {
          int loc = it * 16 + dl;
          *(u16x8v*)&vTb[(size_t)(col0 - 4096 + hh * 128 + loc) * SEQ + nbase + nn] =
              *(const u16x8v*)&T[loc][nn];
        }
        __syncthreads();
      }
    }
  } else if constexpr (MODE == 1) {
    float* C = (float*)Cb + coff;
    const float scale = 0.022097086912079608f;   // 1/sqrt(2048)
#pragma unroll
    for (int m = 0; m < 8; ++m)
#pragma unroll
      for (int n = 0; n < 4; ++n)
#pragma unroll
        for (int r = 0; r < 4; ++r)
          C[(size_t)(rb + m * 16 + l4 + r) * SEQ + cb0 + n * 16 + ln] =
              acc[m][n][r] * scale;
  } else {
    float* C = (float*)Cb + coff;
#pragma unroll
    for (int m = 0; m < 8; ++m)
#pragma unroll
      for (int n = 0; n < 4; ++n)
#pragma unroll
        for (int r = 0; r < 4; ++r)
          C[(size_t)(rb + m * 16 + l4 + r) * SEQ + cb0 + n * 16 + ln] = acc[m][n][r];
  }
}

// ---------------- row softmax: att fp32 -> P bf16 (in place, stride 4096), denom ----------------
// extent is 256-granular to match the 256-tile GEMMs; masked entries produce exp->0.
__global__ __launch_bounds__(256) void softmax_kern(const float* __restrict__ att,
                                                    u16* __restrict__ P,
                                                    float* __restrict__ denom) {
  int row = blockIdx.x;          // b*SEQ + q
  int q = row & (SEQ - 1);
  const float* arow = att + (size_t)row * SEQ;
  u16* prow = P + (size_t)row * 4096;
  int jlen = ((q >> 8) + 1) << 8;          // 256-tile-aligned row extent
  int tid = threadIdx.x;
  int j0 = tid * 4, j1 = tid * 4 + 1024;
  float NI = -__builtin_inff();
  float4 a0 = make_float4(NI, NI, NI, NI), a1 = a0;
  if (j0 < jlen) a0 = *(const float4*)(arow + j0);
  if (j1 < jlen) a1 = *(const float4*)(arow + j1);
  if (j0 + 0 > q) a0.x = NI;
  if (j0 + 1 > q) a0.y = NI;
  if (j0 + 2 > q) a0.z = NI;
  if (j0 + 3 > q) a0.w = NI;
  if (j1 + 0 > q) a1.x = NI;
  if (j1 + 1 > q) a1.y = NI;
  if (j1 + 2 > q) a1.z = NI;
  if (j1 + 3 > q) a1.w = NI;
  float mx = fmaxf(fmaxf(fmaxf(a0.x, a0.y), fmaxf(a0.z, a0.w)),
                   fmaxf(fmaxf(a1.x, a1.y), fmaxf(a1.z, a1.w)));
#pragma unroll
  for (int off = 32; off; off >>= 1) mx = fmaxf(mx, __shfl_xor(mx, off, 64));
  __shared__ float red[8];
  int wv = tid >> 6;
  if ((tid & 63) == 0) red[wv] = mx;
  __syncthreads();
  mx = fmaxf(fmaxf(red[0], red[1]), fmaxf(red[2], red[3]));
  a0.x = expf(a0.x - mx); a0.y = expf(a0.y - mx);
  a0.z = expf(a0.z - mx); a0.w = expf(a0.w - mx);
  a1.x = expf(a1.x - mx); a1.y = expf(a1.y - mx);
  a1.z = expf(a1.z - mx); a1.w = expf(a1.w - mx);
  float s = (a0.x + a0.y + a0.z + a0.w) + (a1.x + a1.y + a1.z + a1.w);
#pragma unroll
  for (int off = 32; off; off >>= 1) s += __shfl_xor(s, off, 64);
  if ((tid & 63) == 0) red[4 + wv] = s;
  __syncthreads();                          // fences all arow reads before P writes
  s = red[4] + red[5] + red[6] + red[7];
  float inv = 1.0f / s;
  if (j0 < jlen) {
    ushort4 u;
    u.x = f2bf(a0.x * inv); u.y = f2bf(a0.y * inv);
    u.z = f2bf(a0.z * inv); u.w = f2bf(a0.w * inv);
    *(ushort4*)(prow + j0) = u;
  }
  if (j1 < jlen) {
    ushort4 u;
    u.x = f2bf(a1.x * inv); u.y = f2bf(a1.y * inv);
    u.z = f2bf(a1.z * inv); u.w = f2bf(a1.w * inv);
    *(ushort4*)(prow + j1) = u;
  }
  if (tid == 0) denom[row] = s;
}

extern "C" void kernel_launch(void* const* d_in, const int* in_sizes, int n_in,
                              void* d_out, int out_size, void* d_ws, size_t ws_size,
                              hipStream_t stream) {
  const float* x    = (const float*)d_in[0];
  const float* W    = (const float*)d_in[1];
  const float* bias = (const float*)d_in[2];

  // ws layout (201,326,592 B):
  //  [0,         67108864)  qk bf16 [8192][4096] (q cols 0..2047, k cols 2048..4095)
  //  [67108864, 100663296)  vT bf16 [4][2048][2048]   (written by gemm<0> epilogue)
  //  [100663296,134217728)  xb bf16 [8192][2048]      (dead after gemm<0>)
  //  [134217728,201326592)  phase1: Wt bf16 (first 25MB, dead after gemm<0>)
  //                         phase2: att fp32 / P bf16 in-place (row stride 4096 u16)
  if (ws_size < 201326592u) return;

  char* w = (char*)d_ws;
  u16*   qk  = (u16*)w;
  u16*   vT  = (u16*)(w + 67108864);
  u16*   xb  = (u16*)(w + 100663296);
  u16*   Wt  = (u16*)(w + 134217728);
  float* att = (float*)(w + 134217728);
  u16*   P   = (u16*)(w + 134217728);

  float* y     = (float*)d_out;
  float* denom = y + (size_t)4 * SEQ * SEQ;

  cast_x_kern<<<16384, 256, 0, stream>>>(x, xb);
  castT_W_kern<<<dim3(96, 32), 256, 0, stream>>>(W, Wt);
  gemm256<0><<<768, 512, 0, stream>>>(xb, Wt, qk, vT, bias);
  gemm256<1><<<144, 512, 0, stream>>>(qk, nullptr, att, nullptr, nullptr);
  softmax_kern<<<8192, 256, 0, stream>>>(att, P, denom);
  gemm256<2><<<256, 512, 0, stream>>>(P, vT, y, nullptr, nullptr);
}

// Round 10
// 328.864 us; speedup vs baseline: 1.6156x; 1.0744x over previous
//
#include <hip/hip_runtime.h>

typedef unsigned short u16;
typedef unsigned int   u32;

#define SEQ 2048
#define EMB 2048
#define TD  6144

using bf16x8 = __attribute__((ext_vector_type(8))) __bf16;
using f32x4  = __attribute__((ext_vector_type(4))) float;
using u16x8v = __attribute__((ext_vector_type(8))) u16;

typedef __attribute__((address_space(1))) const void* gas_t;
typedef __attribute__((address_space(3))) void*       las_t;
#define GLOAD16(g, l) __builtin_amdgcn_global_load_lds((gas_t)(g), (las_t)(l), 16, 0, 0)

__device__ __forceinline__ u16 f2bf(float f) {
  u32 u = __float_as_uint(f);
  u += 0x7fffu + ((u >> 16) & 1u);   // round-to-nearest-even
  return (u16)(u >> 16);
}

// ---------------- cast x (fp32) -> xb (bf16) ----------------
__global__ __launch_bounds__(256) void cast_x_kern(const float* __restrict__ x,
                                                   u16* __restrict__ xb) {
  size_t i = ((size_t)blockIdx.x * 256 + threadIdx.x) * 4;
  float4 v = *(const float4*)(x + i);
  ushort4 u;
  u.x = f2bf(v.x); u.y = f2bf(v.y); u.z = f2bf(v.z); u.w = f2bf(v.w);
  *(ushort4*)(xb + i) = u;
}

// ---------------- cast + transpose W [EMB][TD] -> Wt [TD][EMB] bf16 ----------------
__global__ __launch_bounds__(256) void castT_W_kern(const float* __restrict__ W,
                                                    u16* __restrict__ Wt) {
  __shared__ float t[64][65];
  int c0 = blockIdx.x * 64, r0 = blockIdx.y * 64;
  int tid = threadIdx.x;
#pragma unroll
  for (int i = 0; i < 4; ++i) {
    int flat = i * 1024 + tid * 4;
    int r = flat >> 6, c = flat & 63;
    float4 v = *(const float4*)(W + (size_t)(r0 + r) * TD + c0 + c);
    t[r][c] = v.x; t[r][c + 1] = v.y; t[r][c + 2] = v.z; t[r][c + 3] = v.w;
  }
  __syncthreads();
#pragma unroll
  for (int i = 0; i < 4; ++i) {
    int flat = i * 1024 + tid * 4;
    int wr = flat >> 6, wc = flat & 63;
    ushort4 u;
    u.x = f2bf(t[wc + 0][wr]); u.y = f2bf(t[wc + 1][wr]);
    u.z = f2bf(t[wc + 2][wr]); u.w = f2bf(t[wc + 3][wr]);
    *(ushort4*)(Wt + (size_t)(c0 + wr) * EMB + r0 + wc) = u;
  }
}

// ------------- qkv GEMM: 256x256 tile, 8 waves, R7 pipeline (verbatim revert) -------------
// [qk | vT] = xb @ Wt^T + bias. col<4096 -> qk[8192][4096] bf16;
// col>=4096 -> vT[b][d][n] via in-LDS transpose. grid 768 x 512 thr.
__global__ __launch_bounds__(512, 2) void gemm_qkv(const u16* __restrict__ Ab,
                                                   const u16* __restrict__ Bb,
                                                   u16* __restrict__ Cb,
                                                   u16* __restrict__ Cb2,
                                                   const float* __restrict__ bias) {
  __shared__ char lds[2][65536];
  constexpr int lda = EMB, ldb = EMB;
  int bid = blockIdx.x;
  int wg = (bid & 7) * 96 + (bid >> 3);            // R7 XCD swizzle
  const u16* A = Ab;
  const u16* Bt = Bb;
  int row0 = (wg / 24) * 256, col0 = (wg % 24) * 256, nk = EMB / 64;

  int tid = threadIdx.x;
  int wave = tid >> 6, lane = tid & 63;
  int wm = wave >> 2, wn = wave & 3;

  int sbase[8];
#pragma unroll
  for (int i = 0; i < 4; ++i) sbase[i] = 32768 + i * 8192 + wave * 1024;
#pragma unroll
  for (int i = 0; i < 4; ++i)
    sbase[4 + i] = i * 4096 + ((wave < 4) ? wave * 1024 : 16384 + (wave - 4) * 1024);

  auto stageb = [&](int bi, int t, int buf) {
    int ob = sbase[bi];
    int obl = ob + lane * 16;
    int row = (obl & 32767) >> 7;
    int cb = obl & 127;
    int c = ((cb ^ ((row & 7) << 4)) >> 1) + t * 64;
    const u16* src = (ob < 32768) ? (A + (size_t)(row0 + row) * lda + c)
                                  : (Bt + (size_t)(col0 + row) * ldb + c);
    GLOAD16(src, (char*)&lds[buf][0] + ob);
  };
  auto ldA = [&](int buf, int rr, int ks) -> bf16x8 {
    int cb = ks * 64 + (lane >> 4) * 16;
    return *(const bf16x8*)&lds[buf][rr * 128 + (cb ^ ((rr & 7) << 4))];
  };
  auto ldB = [&](int buf, int rr, int ks) -> bf16x8 {
    int cb = ks * 64 + (lane >> 4) * 16;
    return *(const bf16x8*)&lds[buf][32768 + rr * 128 + (cb ^ ((rr & 7) << 4))];
  };

  f32x4 acc[8][4];
#pragma unroll
  for (int m = 0; m < 8; ++m)
#pragma unroll
    for (int n = 0; n < 4; ++n) acc[m][n] = (f32x4){0.f, 0.f, 0.f, 0.f};

#pragma unroll
  for (int bi = 0; bi < 8; ++bi) stageb(bi, 0, 0);
#pragma unroll
  for (int bi = 0; bi < 6; ++bi) stageb(bi, 1, 1);
  asm volatile("s_waitcnt vmcnt(6)" ::: "memory");
  __builtin_amdgcn_s_barrier();

  bf16x8 bfg[4][2];
  for (int t = 0; t < nk; ++t) {
    int cur = t & 1, nxt = cur ^ 1;
    bool pf1 = (t + 1 < nk), pf2 = (t + 2 < nk);
    bf16x8 afg[2][2];
    // p0
#pragma unroll
    for (int n = 0; n < 4; ++n)
#pragma unroll
      for (int ks = 0; ks < 2; ++ks)
        bfg[n][ks] = ldB(cur, wn * 64 + n * 16 + (lane & 15), ks);
#pragma unroll
    for (int m = 0; m < 2; ++m)
#pragma unroll
      for (int ks = 0; ks < 2; ++ks)
        afg[m][ks] = ldA(cur, wm * 128 + m * 16 + (lane & 15), ks);
    if (pf1) { stageb(6, t + 1, nxt); stageb(7, t + 1, nxt); }
    __builtin_amdgcn_s_setprio(1);
#pragma unroll
    for (int m = 0; m < 2; ++m)
#pragma unroll
      for (int n = 0; n < 4; ++n)
#pragma unroll
        for (int ks = 0; ks < 2; ++ks)
          acc[m][n] = __builtin_amdgcn_mfma_f32_16x16x32_bf16(
              afg[m][ks], bfg[n][ks], acc[m][n], 0, 0, 0);
    __builtin_amdgcn_s_setprio(0);
    __builtin_amdgcn_s_barrier();
    // p1 (no barrier)
#pragma unroll
    for (int m = 0; m < 2; ++m)
#pragma unroll
      for (int ks = 0; ks < 2; ++ks)
        afg[m][ks] = ldA(cur, wm * 128 + (2 + m) * 16 + (lane & 15), ks);
    if (pf2) { stageb(0, t + 2, cur); stageb(1, t + 2, cur); }
    __builtin_amdgcn_s_setprio(1);
#pragma unroll
    for (int m = 0; m < 2; ++m)
#pragma unroll
      for (int n = 0; n < 4; ++n)
#pragma unroll
        for (int ks = 0; ks < 2; ++ks)
          acc[2 + m][n] = __builtin_amdgcn_mfma_f32_16x16x32_bf16(
              afg[m][ks], bfg[n][ks], acc[2 + m][n], 0, 0, 0);
    __builtin_amdgcn_s_setprio(0);
    // p2
#pragma unroll
    for (int m = 0; m < 2; ++m)
#pragma unroll
      for (int ks = 0; ks < 2; ++ks)
        afg[m][ks] = ldA(cur, wm * 128 + (4 + m) * 16 + (lane & 15), ks);
    if (pf2) { stageb(2, t + 2, cur); stageb(3, t + 2, cur); }
    __builtin_amdgcn_s_setprio(1);
#pragma unroll
    for (int m = 0; m < 2; ++m)
#pragma unroll
      for (int n = 0; n < 4; ++n)
#pragma unroll
        for (int ks = 0; ks < 2; ++ks)
          acc[4 + m][n] = __builtin_amdgcn_mfma_f32_16x16x32_bf16(
              afg[m][ks], bfg[n][ks], acc[4 + m][n], 0, 0, 0);
    __builtin_amdgcn_s_setprio(0);
    __builtin_amdgcn_s_barrier();
    // p3
#pragma unroll
    for (int m = 0; m < 2; ++m)
#pragma unroll
      for (int ks = 0; ks < 2; ++ks)
        afg[m][ks] = ldA(cur, wm * 128 + (6 + m) * 16 + (lane & 15), ks);
    if (pf2) { stageb(4, t + 2, cur); stageb(5, t + 2, cur); }
    __builtin_amdgcn_s_setprio(1);
#pragma unroll
    for (int m = 0; m < 2; ++m)
#pragma unroll
      for (int n = 0; n < 4; ++n)
#pragma unroll
        for (int ks = 0; ks < 2; ++ks)
          acc[6 + m][n] = __builtin_amdgcn_mfma_f32_16x16x32_bf16(
              afg[m][ks], bfg[n][ks], acc[6 + m][n], 0, 0, 0);
    __builtin_amdgcn_s_setprio(0);
    if (pf2)      asm volatile("s_waitcnt vmcnt(6)" ::: "memory");
    else if (pf1) asm volatile("s_waitcnt vmcnt(0)" ::: "memory");
    __builtin_amdgcn_s_barrier();
  }

  int ln = lane & 15;
  int l4 = (lane >> 4) << 2;
  int rb = row0 + wm * 128, cb0 = col0 + wn * 64;
  if (col0 < 4096) {
    u16* C = Cb;
#pragma unroll
    for (int n = 0; n < 4; ++n) {
      float bv = bias[cb0 + n * 16 + ln];
#pragma unroll
      for (int m = 0; m < 8; ++m)
#pragma unroll
        for (int r = 0; r < 4; ++r)
          C[(size_t)(rb + m * 16 + l4 + r) * 4096 + cb0 + n * 16 + ln] =
              f2bf(acc[m][n][r] + bv);
    }
  } else {
    u16* vTb = Cb2 + (size_t)(row0 >> 11) * SEQ * SEQ;
    int nbase = row0 & 2047;
    u16 (*T)[264] = (u16(*)[264])(&lds[0][0]);
    int half = wn >> 1;
    int dloc0 = (wn & 1) * 64;
#pragma unroll
    for (int hh = 0; hh < 2; ++hh) {
      if (half == hh) {
#pragma unroll
        for (int n = 0; n < 4; ++n) {
          float bv = bias[cb0 + n * 16 + ln];
          int dl = dloc0 + n * 16 + ln;
#pragma unroll
          for (int m = 0; m < 8; ++m) {
            int nn = wm * 128 + m * 16 + l4;
#pragma unroll
            for (int r = 0; r < 4; ++r)
              T[dl][nn + r] = f2bf(acc[m][n][r] + bv);
          }
        }
      }
      __syncthreads();
      int dl = tid >> 5, nn = (tid & 31) * 8;
#pragma unroll
      for (int it = 0; it < 8; ++it) {
        int loc = it * 16 + dl;
        *(u16x8v*)&vTb[(size_t)(col0 - 4096 + hh * 128 + loc) * SEQ + nbase + nn] =
            *(const u16x8v*)&T[loc][nn];
      }
      __syncthreads();
    }
  }
}

// ------------- 128x128 NT GEMM, 4 waves, 64KB LDS -> 2 blocks/CU -------------
// 2 phases per K-step: p0 reads B(all)+A m0,m1; p1 reads A m2,m3.
// Bundles (4KB each): b0..b3 = B rows 0-127; b4..b7 = A rows 0-31/32-63/64-95/96-127.
// Consumption: p0 uses B + A bundles {4,6}; p1 uses A bundles {5,7}.
// Stage: t.p0 -> t+1's {5,7} into nxt; t.p1 -> t+2's {0,1,2,3,4,6} into cur (regions
// consumed at p0). Boundary vmcnt(6) drains exactly tile t+1 (R7-identical invariant).
// MODE 1: att = scale * q @ k^T (strides 4096), causal 128-tile triangle. grid 544.
// MODE 2: y = P @ vT^T, K=(qi+1)*128, qi-descending dispatch. grid 1024.
template <int MODE>
__global__ __launch_bounds__(256, 2) void gemm128(const u16* __restrict__ Ab,
                                                  const u16* __restrict__ Bb,
                                                  float* __restrict__ Cb) {
  __shared__ char lds[2][32768];
  constexpr int lda = 4096;
  constexpr int ldb = (MODE == 1) ? 4096 : SEQ;

  int bid = blockIdx.x;
  const u16 *A, *Bt;
  int row0, col0, nk;
  size_t coff;
  if constexpr (MODE == 1) {
    constexpr int CPX = 544 / 8;
    int wg = (bid & 7) * CPX + (bid >> 3);
    int b = wg / 136, tq = wg % 136;
    int qi = (int)((sqrtf(8.f * (float)tq + 1.f) - 1.f) * 0.5f);
    while ((qi + 1) * (qi + 2) / 2 <= tq) ++qi;
    while (qi * (qi + 1) / 2 > tq) --qi;
    int kj = tq - qi * (qi + 1) / 2;
    A = Ab + (size_t)b * SEQ * 4096;       // q slice
    Bt = A + 2048;                         // k slice
    row0 = qi * 128; col0 = kj * 128; nk = EMB / 64;
    coff = (size_t)b * SEQ * SEQ;
  } else {
    // qi-descending: heavy blocks dispatched first. 64 blocks per qi (8 per XCD).
    int xcd = bid & 7, idx = bid >> 3;     // idx 0..127
    int qi = 15 - (idx >> 3);
    int g = xcd * 8 + (idx & 7);           // 0..63
    int b = g >> 4, nj = g & 15;
    A = Ab + (size_t)b * SEQ * 4096;       // P, stride 4096
    Bt = Bb + (size_t)b * SEQ * SEQ;       // vT
    row0 = qi * 128; col0 = nj * 128; nk = (qi + 1) * 2;
    coff = (size_t)b * SEQ * SEQ;
  }

  int tid = threadIdx.x;
  int wave = tid >> 6, lane = tid & 63;
  int wm = wave >> 1, wn = wave & 1;       // 2x2 wave grid, 64x64 out each
  int ln = lane & 15;

  // b0..b3 = B bundle i (rows i*32..i*32+31); b4..b7 = A bundle (same row split)
  int sbase[8];
#pragma unroll
  for (int i = 0; i < 4; ++i) sbase[i] = 16384 + i * 4096 + wave * 1024;
#pragma unroll
  for (int i = 0; i < 4; ++i) sbase[4 + i] = i * 4096 + wave * 1024;

  auto stageb = [&](int bi, int t, int buf) {
    int ob = sbase[bi];
    int obl = ob + lane * 16;
    int row = (obl & 16383) >> 7;
    int cb = obl & 127;
    int c = ((cb ^ ((row & 7) << 4)) >> 1) + t * 64;
    const u16* src = (ob < 16384) ? (A + (size_t)(row0 + row) * lda + c)
                                  : (Bt + (size_t)(col0 + row) * ldb + c);
    GLOAD16(src, (char*)&lds[buf][0] + ob);
  };
  auto ldA = [&](int buf, int rr, int ks) -> bf16x8 {
    int cb = ks * 64 + (lane >> 4) * 16;
    return *(const bf16x8*)&lds[buf][rr * 128 + (cb ^ ((rr & 7) << 4))];
  };
  auto ldB = [&](int buf, int rr, int ks) -> bf16x8 {
    int cb = ks * 64 + (lane >> 4) * 16;
    return *(const bf16x8*)&lds[buf][16384 + rr * 128 + (cb ^ ((rr & 7) << 4))];
  };

  f32x4 acc[4][4];
#pragma unroll
  for (int m = 0; m < 4; ++m)
#pragma unroll
    for (int n = 0; n < 4; ++n) acc[m][n] = (f32x4){0.f, 0.f, 0.f, 0.f};

  // prologue: tile0 fully; tile1 bundles {0,1,2,3,4,6}; vmcnt(6) -> tile0 landed
#pragma unroll
  for (int bi = 0; bi < 8; ++bi) stageb(bi, 0, 0);
  stageb(0, 1, 1); stageb(1, 1, 1); stageb(2, 1, 1); stageb(3, 1, 1);
  stageb(4, 1, 1); stageb(6, 1, 1);
  asm volatile("s_waitcnt vmcnt(6)" ::: "memory");
  __builtin_amdgcn_s_barrier();

  bf16x8 bfg[4][2];
  for (int t = 0; t < nk; ++t) {
    int cur = t & 1, nxt = cur ^ 1;
    bool pf1 = (t + 1 < nk), pf2 = (t + 2 < nk);
    bf16x8 afg[2][2];
    // ---- p0: read B(8) + A m0,m1 (bundles 4,6); stage t+1 {5,7} -> nxt; MFMA; BARRIER ----
#pragma unroll
    for (int n = 0; n < 4; ++n)
#pragma unroll
      for (int ks = 0; ks < 2; ++ks)
        bfg[n][ks] = ldB(cur, wn * 64 + n * 16 + ln, ks);
#pragma unroll
    for (int m = 0; m < 2; ++m)
#pragma unroll
      for (int ks = 0; ks < 2; ++ks)
        afg[m][ks] = ldA(cur, wm * 64 + m * 16 + ln, ks);
    if (pf1) { stageb(5, t + 1, nxt); stageb(7, t + 1, nxt); }
    __builtin_amdgcn_s_setprio(1);
#pragma unroll
    for (int m = 0; m < 2; ++m)
#pragma unroll
      for (int n = 0; n < 4; ++n)
#pragma unroll
        for (int ks = 0; ks < 2; ++ks)
          acc[m][n] = __builtin_amdgcn_mfma_f32_16x16x32_bf16(
              afg[m][ks], bfg[n][ks], acc[m][n], 0, 0, 0);
    __builtin_amdgcn_s_setprio(0);
    __builtin_amdgcn_s_barrier();
    // ---- p1: read A m2,m3 (bundles 5,7); stage t+2 {0..4,6} -> cur; MFMA; vmcnt; BARRIER ----
#pragma unroll
    for (int m = 0; m < 2; ++m)
#pragma unroll
      for (int ks = 0; ks < 2; ++ks)
        afg[m][ks] = ldA(cur, wm * 64 + (2 + m) * 16 + ln, ks);
    if (pf2) {
      stageb(0, t + 2, cur); stageb(1, t + 2, cur); stageb(2, t + 2, cur);
      stageb(3, t + 2, cur); stageb(4, t + 2, cur); stageb(6, t + 2, cur);
    }
    __builtin_amdgcn_s_setprio(1);
#pragma unroll
    for (int m = 0; m < 2; ++m)
#pragma unroll
      for (int n = 0; n < 4; ++n)
#pragma unroll
        for (int ks = 0; ks < 2; ++ks)
          acc[2 + m][n] = __builtin_amdgcn_mfma_f32_16x16x32_bf16(
              afg[m][ks], bfg[n][ks], acc[2 + m][n], 0, 0, 0);
    __builtin_amdgcn_s_setprio(0);
    if (pf2)      asm volatile("s_waitcnt vmcnt(6)" ::: "memory");
    else if (pf1) asm volatile("s_waitcnt vmcnt(0)" ::: "memory");
    __builtin_amdgcn_s_barrier();
  }

  int l4 = (lane >> 4) << 2;
  int rb = row0 + wm * 64, cb0 = col0 + wn * 64;
  float* C = Cb + coff;
  const float scale = (MODE == 1) ? 0.022097086912079608f : 1.0f;  // 1/sqrt(2048)
#pragma unroll
  for (int m = 0; m < 4; ++m)
#pragma unroll
    for (int n = 0; n < 4; ++n)
#pragma unroll
      for (int r = 0; r < 4; ++r)
        C[(size_t)(rb + m * 16 + l4 + r) * SEQ + cb0 + n * 16 + ln] =
            acc[m][n][r] * scale;
}

// ---------------- row softmax: att fp32 -> P bf16 (in place, stride 4096), denom ----------------
// extent is 128-granular to match the 128-tile attention GEMMs; masked entries exp->0.
__global__ __launch_bounds__(256) void softmax_kern(const float* __restrict__ att,
                                                    u16* __restrict__ P,
                                                    float* __restrict__ denom) {
  int row = blockIdx.x;          // b*SEQ + q
  int q = row & (SEQ - 1);
  const float* arow = att + (size_t)row * SEQ;
  u16* prow = P + (size_t)row * 4096;
  int jlen = ((q >> 7) + 1) << 7;          // 128-tile-aligned row extent
  int tid = threadIdx.x;
  int j0 = tid * 4, j1 = tid * 4 + 1024;
  float NI = -__builtin_inff();
  float4 a0 = make_float4(NI, NI, NI, NI), a1 = a0;
  if (j0 < jlen) a0 = *(const float4*)(arow + j0);
  if (j1 < jlen) a1 = *(const float4*)(arow + j1);
  if (j0 + 0 > q) a0.x = NI;
  if (j0 + 1 > q) a0.y = NI;
  if (j0 + 2 > q) a0.z = NI;
  if (j0 + 3 > q) a0.w = NI;
  if (j1 + 0 > q) a1.x = NI;
  if (j1 + 1 > q) a1.y = NI;
  if (j1 + 2 > q) a1.z = NI;
  if (j1 + 3 > q) a1.w = NI;
  float mx = fmaxf(fmaxf(fmaxf(a0.x, a0.y), fmaxf(a0.z, a0.w)),
                   fmaxf(fmaxf(a1.x, a1.y), fmaxf(a1.z, a1.w)));
#pragma unroll
  for (int off = 32; off; off >>= 1) mx = fmaxf(mx, __shfl_xor(mx, off, 64));
  __shared__ float red[8];
  int wv = tid >> 6;
  if ((tid & 63) == 0) red[wv] = mx;
  __syncthreads();
  mx = fmaxf(fmaxf(red[0], red[1]), fmaxf(red[2], red[3]));
  a0.x = expf(a0.x - mx); a0.y = expf(a0.y - mx);
  a0.z = expf(a0.z - mx); a0.w = expf(a0.w - mx);
  a1.x = expf(a1.x - mx); a1.y = expf(a1.y - mx);
  a1.z = expf(a1.z - mx); a1.w = expf(a1.w - mx);
  float s = (a0.x + a0.y + a0.z + a0.w) + (a1.x + a1.y + a1.z + a1.w);
#pragma unroll
  for (int off = 32; off; off >>= 1) s += __shfl_xor(s, off, 64);
  if ((tid & 63) == 0) red[4 + wv] = s;
  __syncthreads();                          // fences all arow reads before P writes
  s = red[4] + red[5] + red[6] + red[7];
  float inv = 1.0f / s;
  if (j0 < jlen) {
    ushort4 u;
    u.x = f2bf(a0.x * inv); u.y = f2bf(a0.y * inv);
    u.z = f2bf(a0.z * inv); u.w = f2bf(a0.w * inv);
    *(ushort4*)(prow + j0) = u;
  }
  if (j1 < jlen) {
    ushort4 u;
    u.x = f2bf(a1.x * inv); u.y = f2bf(a1.y * inv);
    u.z = f2bf(a1.z * inv); u.w = f2bf(a1.w * inv);
    *(ushort4*)(prow + j1) = u;
  }
  if (tid == 0) denom[row] = s;
}

extern "C" void kernel_launch(void* const* d_in, const int* in_sizes, int n_in,
                              void* d_out, int out_size, void* d_ws, size_t ws_size,
                              hipStream_t stream) {
  const float* x    = (const float*)d_in[0];
  const float* W    = (const float*)d_in[1];
  const float* bias = (const float*)d_in[2];

  // ws layout (201,326,592 B):
  //  [0,         67108864)  qk bf16 [8192][4096] (q cols 0..2047, k cols 2048..4095)
  //  [67108864, 100663296)  vT bf16 [4][2048][2048]   (written by gemm_qkv epilogue)
  //  [100663296,134217728)  xb bf16 [8192][2048]      (dead after gemm_qkv)
  //  [134217728,201326592)  phase1: Wt bf16 (first 25MB, dead after gemm_qkv)
  //                         phase2: att fp32 / P bf16 in-place (row stride 4096 u16)
  if (ws_size < 201326592u) return;

  char* w = (char*)d_ws;
  u16*   qk  = (u16*)w;
  u16*   vT  = (u16*)(w + 67108864);
  u16*   xb  = (u16*)(w + 100663296);
  u16*   Wt  = (u16*)(w + 134217728);
  float* att = (float*)(w + 134217728);
  u16*   P   = (u16*)(w + 134217728);

  float* y     = (float*)d_out;
  float* denom = y + (size_t)4 * SEQ * SEQ;

  cast_x_kern<<<16384, 256, 0, stream>>>(x, xb);
  castT_W_kern<<<dim3(96, 32), 256, 0, stream>>>(W, Wt);
  gemm_qkv<<<768, 512, 0, stream>>>(xb, Wt, qk, vT, bias);
  gemm128<1><<<544, 256, 0, stream>>>(qk, nullptr, att);
  softmax_kern<<<8192, 256, 0, stream>>>(att, P, denom);
  gemm128<2><<<1024, 256, 0, stream>>>(P, vT, y);
}